// Round 7
// baseline (483.183 us; speedup 1.0000x reference)
//
#include <hip/hip_runtime.h>
#include <math.h>

#define NNODES 50000
#define NEG_SLOPE 0.2f

typedef unsigned short ushort8v __attribute__((ext_vector_type(8)));
typedef unsigned short ushort4v __attribute__((ext_vector_type(4)));
typedef short short8v __attribute__((ext_vector_type(8)));
typedef float f32x4 __attribute__((ext_vector_type(4)));
typedef float f32x2 __attribute__((ext_vector_type(2)));

__device__ __forceinline__ float bf2f(unsigned short u){ return __uint_as_float(((unsigned)u) << 16); }
__device__ __forceinline__ unsigned short f2bf(float f){
    unsigned u = __float_as_uint(f);
    u += 0x7fff + ((u >> 16) & 1);   // RNE; inputs finite
    return (unsigned short)(u >> 16);
}

// ---------------- edge dtype detection + conversion ----------------
__global__ void detect_kernel(const unsigned long long* __restrict__ e, int* __restrict__ flag){
    const unsigned long long v = e[threadIdx.x & 63];
    const unsigned long long mask = __ballot(v >= (1ULL << 32));
    if(threadIdx.x == 0) *flag = (mask == 0ULL) ? 1 : 0;
}

// convert + fused degree histogram (dst half only)
__global__ void convert_kernel(const void* __restrict__ e, const int* __restrict__ flag,
                               int* __restrict__ out, int* __restrict__ deg,
                               int total, int E){
    int i = blockIdx.x * blockDim.x + threadIdx.x;
    if(i < total){
        int v;
        if(*flag) v = (int)((const long long*)e)[i];
        else      v = ((const int*)e)[i];
        out[i] = v;
        if(i >= E) atomicAdd(&deg[v], 1);
    }
}

// ---------------- bf16 packing of x ----------------
__global__ void f2bf_kernel(const float* __restrict__ in, unsigned short* __restrict__ out, int total4){
    const int i = blockIdx.x * blockDim.x + threadIdx.x;
    if(i < total4){
        const float4 v = *(const float4*)&in[(size_t)i * 4];
        ushort4v o;
        o[0] = f2bf(v.x); o[1] = f2bf(v.y); o[2] = f2bf(v.z); o[3] = f2bf(v.w);
        *(ushort4v*)&out[(size_t)i * 4] = o;
    }
}

// ---------------- weight prep: Wt[NC+8][K] = [W^T ; ws ; wd] in bf16 ----------------
// rows 0..NC-1: W transposed. rows NC+h (h<4): ws[k,h]=sum_c W[k,hC+c]*as[h,c];
// rows NC+4+h: wd likewise. Appending ws/wd lets the GEMM emit aS/aD directly
// (alpha is linear in x: aS = x @ (W @ a_s)).
__device__ __forceinline__ void emit_wt(const float* __restrict__ W, const float* __restrict__ a_s,
                                        const float* __restrict__ a_d, unsigned short* __restrict__ Wt,
                                        int K, int NC, int C, int id){
    const int n = id / K, k = id - n * K;
    float v;
    if(n < NC){
        v = W[(size_t)k * NC + n];
    } else {
        const int h = n - NC;
        const int hh = h & 3;
        const float* av = (h < 4) ? a_s : a_d;
        v = 0.f;
        for(int c = 0; c < C; c++) v += W[(size_t)k * NC + hh * C + c] * av[hh * C + c];
    }
    Wt[(size_t)n * K + k] = f2bf(v);
}

__global__ void prep_kernel(const float* __restrict__ W1, const float* __restrict__ as1, const float* __restrict__ ad1,
                            const float* __restrict__ W2, const float* __restrict__ as2, const float* __restrict__ ad2,
                            const float* __restrict__ W3, const float* __restrict__ as3, const float* __restrict__ ad3,
                            unsigned short* __restrict__ W1t, unsigned short* __restrict__ W2t,
                            unsigned short* __restrict__ W3t){
    int id = blockIdx.x * blockDim.x + threadIdx.x;
    if(id < 264 * 128){ emit_wt(W1, as1, ad1, W1t, 128, 256, 64, id); return; }
    id -= 264 * 128;
    if(id < 264 * 64){ emit_wt(W2, as2, ad2, W2t, 64, 256, 64, id); return; }
    id -= 264 * 64;
    if(id < 168 * 64){ emit_wt(W3, as3, ad3, W3t, 64, 160, 40, id); }
}

// ---------------- CSR build (hierarchical scan) ----------------
__global__ __launch_bounds__(512) void scan1_kernel(const int* __restrict__ deg,
                                                    int* __restrict__ excl,
                                                    int* __restrict__ bsum, int n){
    __shared__ int sh[512];
    const int t = threadIdx.x;
    const int gid = blockIdx.x * 512 + t;
    const int v = (gid < n) ? deg[gid] : 0;
    sh[t] = v;
    __syncthreads();
    for(int off = 1; off < 512; off <<= 1){
        const int add = (t >= off) ? sh[t - off] : 0;
        __syncthreads();
        sh[t] += add;
        __syncthreads();
    }
    if(gid < n) excl[gid] = sh[t] - v;
    if(t == 511) bsum[blockIdx.x] = sh[511];
}

__global__ __launch_bounds__(128) void scan2_kernel(int* __restrict__ bsum, int nb){
    __shared__ int sh[128];
    const int t = threadIdx.x;
    const int v = (t < nb) ? bsum[t] : 0;
    sh[t] = v;
    __syncthreads();
    for(int off = 1; off < 128; off <<= 1){
        const int add = (t >= off) ? sh[t - off] : 0;
        __syncthreads();
        sh[t] += add;
        __syncthreads();
    }
    if(t < nb) bsum[t] = sh[t] - v;
}

__global__ void scan3_kernel(const int* __restrict__ excl, const int* __restrict__ bsum,
                             int* __restrict__ row_ptr, int* __restrict__ cursor,
                             int n, int E){
    const int gid = blockIdx.x * blockDim.x + threadIdx.x;
    if(gid < n){
        const int r = excl[gid] + bsum[gid >> 9];
        row_ptr[gid] = r;
        cursor[gid] = r;
    }
    if(gid == 0) row_ptr[n] = E;
}

__global__ void scatter_kernel(const int* __restrict__ src, const int* __restrict__ dst,
                               int* __restrict__ cursor, int* __restrict__ col, int E){
    int i = blockIdx.x * blockDim.x + threadIdx.x;
    if(i < E){
        int d = dst[i];
        int pos = atomicAdd(&cursor[d], 1);
        col[pos] = src[i];
    }
}

// ---------------- MFMA bf16 GEMM + fused alpha/exp epilogue ----------------
// C[M,NC] = A[M,K] * Bt[0:NC,K]^T; extra tile (rows NC..NC+7 of Bt) yields
// aS (h=0..3) and aD (h=4..7); epilogue stores ea=(exp(aS),exp(.2 aS)) and
// ed likewise. Single y-block: A read once, all NT tiles in registers.
template<int K, int NC>
__global__ __launch_bounds__(256) void mfma_gemm_kernel(const unsigned short* __restrict__ A,
                                                        const unsigned short* __restrict__ Bt,
                                                        unsigned short* __restrict__ C,
                                                        f32x2* __restrict__ ea,
                                                        f32x2* __restrict__ ed,
                                                        int M){
    constexpr int NT = NC / 16 + 1;
    const int lane = threadIdx.x & 63;
    const int wave = threadIdx.x >> 6;
    const int quad = lane >> 4;
    const int l16 = lane & 15;
    const int bm = blockIdx.x * 64;
    const int m = min(bm + wave * 16 + l16, M - 1);
    const size_t arow = (size_t)m * K;

    f32x4 acc[NT];
    #pragma unroll
    for(int t = 0; t < NT; t++) acc[t] = (f32x4){0,0,0,0};
    int cn[NT];
    #pragma unroll
    for(int t = 0; t < NT; t++) cn[t] = min(t * 16 + l16, NC + 7);

    for(int k0 = 0; k0 < K; k0 += 32){
        const short8v a = *(const short8v*)&A[arow + k0 + quad * 8];
        #pragma unroll
        for(int t = 0; t < NT; t++){
            const short8v b = *(const short8v*)&Bt[(size_t)cn[t] * K + k0 + quad * 8];
            acc[t] = __builtin_amdgcn_mfma_f32_16x16x32_bf16(a, b, acc[t], 0, 0, 0);
        }
    }
    const int rbase = bm + wave * 16 + quad * 4;
    #pragma unroll
    for(int t = 0; t < NT - 1; t++){
        const int c = t * 16 + l16;
        #pragma unroll
        for(int r = 0; r < 4; r++){
            const int row = rbase + r;
            if(row < M) C[(size_t)row * NC + c] = f2bf(acc[t][r]);
        }
    }
    if(l16 < 8){
        const int h = l16 & 3;
        f32x2* dst = (l16 < 4) ? ea : ed;
        #pragma unroll
        for(int r = 0; r < 4; r++){
            const int row = rbase + r;
            if(row < M){
                const float v = acc[NT - 1][r];
                f32x2 e2 = {__expf(v), __expf(NEG_SLOPE * v)};
                dst[(size_t)row * 4 + h] = e2;
            }
        }
    }
}

// ---------------- fused softmax + weighted gather ----------------
// w = exp(lrelu(aS+aD)) = max(exp(aS)exp(aD), exp(.2aS)exp(.2aD)) -- no
// transcendental in the loop. bf16 pairs unpacked by shift/mask into packed
// f32x2 FMA. denom accumulated in-pass; divide at end. 4 edges in flight.
template<int C, bool FINAL>
__global__ __launch_bounds__(256) void gather_kernel(const unsigned short* __restrict__ xp,
                                                     const int* __restrict__ row_ptr,
                                                     const int* __restrict__ col,
                                                     const f32x2* __restrict__ ea,
                                                     const f32x2* __restrict__ ed,
                                                     const float* __restrict__ bias,
                                                     void* __restrict__ outv){
    constexpr int HC = 4 * C;
    constexpr int LPE = HC / 8;     // lanes per edge: 32 or 20
    __shared__ float sbuf[4][FINAL ? HC : 1];
    const int lane = threadIdx.x & 63;
    const int wave = threadIdx.x >> 6;
    const int n = blockIdx.x * 4 + wave;
    const int half = lane >> 5;
    const int hl = lane & 31;
    const bool active = hl < LPE;
    const int head = min((8 * hl) / C, 3);
    const int rs = row_ptr[n], re = row_ptr[n + 1];
    const int T = re - rs + 1;      // edges + virtual self loop
    const f32x2 edh = ed[(size_t)n * 4 + head];
    const unsigned short* xpl = xp + 8 * hl;

    f32x2 acc2[4] = {{0,0},{0,0},{0,0},{0,0}};
    float denom = 0.f;
    int k = 0;
    for(; k + 4 <= T; k += 4){
        const int eA = rs + k + half;
        const int eB = eA + 2;
        const int sA = (eA < re) ? col[eA] : n;
        const int sB = (eB < re) ? col[eB] : n;
        const f32x2 a2 = ea[(size_t)sA * 4 + head];
        const f32x2 b2 = ea[(size_t)sB * 4 + head];
        const float wA = fmaxf(a2[0] * edh[0], a2[1] * edh[1]);
        const float wB = fmaxf(b2[0] * edh[0], b2[1] * edh[1]);
        denom += wA + wB;
        if(active){
            const uint4 uA = *(const uint4*)&xpl[(size_t)sA * HC];
            const uint4 uB = *(const uint4*)&xpl[(size_t)sB * HC];
            const f32x2 wA2 = {wA, wA};
            const f32x2 wB2 = {wB, wB};
            acc2[0] += wA2 * (f32x2){__uint_as_float(uA.x << 16), __uint_as_float(uA.x & 0xffff0000u)};
            acc2[1] += wA2 * (f32x2){__uint_as_float(uA.y << 16), __uint_as_float(uA.y & 0xffff0000u)};
            acc2[2] += wA2 * (f32x2){__uint_as_float(uA.z << 16), __uint_as_float(uA.z & 0xffff0000u)};
            acc2[3] += wA2 * (f32x2){__uint_as_float(uA.w << 16), __uint_as_float(uA.w & 0xffff0000u)};
            acc2[0] += wB2 * (f32x2){__uint_as_float(uB.x << 16), __uint_as_float(uB.x & 0xffff0000u)};
            acc2[1] += wB2 * (f32x2){__uint_as_float(uB.y << 16), __uint_as_float(uB.y & 0xffff0000u)};
            acc2[2] += wB2 * (f32x2){__uint_as_float(uB.z << 16), __uint_as_float(uB.z & 0xffff0000u)};
            acc2[3] += wB2 * (f32x2){__uint_as_float(uB.w << 16), __uint_as_float(uB.w & 0xffff0000u)};
        }
    }
    for(; k + 2 <= T; k += 2){
        const int e = rs + k + half;
        const int s = (e < re) ? col[e] : n;
        const f32x2 a2 = ea[(size_t)s * 4 + head];
        const float wh = fmaxf(a2[0] * edh[0], a2[1] * edh[1]);
        denom += wh;
        if(active){
            const uint4 u = *(const uint4*)&xpl[(size_t)s * HC];
            const f32x2 w2 = {wh, wh};
            acc2[0] += w2 * (f32x2){__uint_as_float(u.x << 16), __uint_as_float(u.x & 0xffff0000u)};
            acc2[1] += w2 * (f32x2){__uint_as_float(u.y << 16), __uint_as_float(u.y & 0xffff0000u)};
            acc2[2] += w2 * (f32x2){__uint_as_float(u.z << 16), __uint_as_float(u.z & 0xffff0000u)};
            acc2[3] += w2 * (f32x2){__uint_as_float(u.w << 16), __uint_as_float(u.w & 0xffff0000u)};
        }
    }
    if(k < T && half == 0){
        const int e = rs + k;
        const int s = (e < re) ? col[e] : n;
        const f32x2 a2 = ea[(size_t)s * 4 + head];
        const float wh = fmaxf(a2[0] * edh[0], a2[1] * edh[1]);
        denom += wh;
        if(active){
            const uint4 u = *(const uint4*)&xpl[(size_t)s * HC];
            const f32x2 w2 = {wh, wh};
            acc2[0] += w2 * (f32x2){__uint_as_float(u.x << 16), __uint_as_float(u.x & 0xffff0000u)};
            acc2[1] += w2 * (f32x2){__uint_as_float(u.y << 16), __uint_as_float(u.y & 0xffff0000u)};
            acc2[2] += w2 * (f32x2){__uint_as_float(u.z << 16), __uint_as_float(u.z & 0xffff0000u)};
            acc2[3] += w2 * (f32x2){__uint_as_float(u.w << 16), __uint_as_float(u.w & 0xffff0000u)};
        }
    }
    // merge halves (xor-32 partner has same hl -> same head)
    #pragma unroll
    for(int p = 0; p < 4; p++){
        acc2[p][0] += __shfl_xor(acc2[p][0], 32);
        acc2[p][1] += __shfl_xor(acc2[p][1], 32);
    }
    denom += __shfl_xor(denom, 32);
    const float ih = 1.f / denom;
    float acc[8];
    #pragma unroll
    for(int p = 0; p < 4; p++){ acc[2*p] = acc2[p][0] * ih; acc[2*p+1] = acc2[p][1] * ih; }

    if(!FINAL){
        #pragma unroll
        for(int j = 0; j < 8; j++){
            acc[j] += __shfl_xor(acc[j], 8);
            acc[j] += __shfl_xor(acc[j], 16);
        }
        if(lane < 8){
            unsigned short* out = (unsigned short*)outv;
            ushort8v o;
            #pragma unroll
            for(int j = 0; j < 8; j++)
                o[j] = f2bf(fmaxf(acc[j] * 0.25f + bias[8 * lane + j], 0.f));
            *(ushort8v*)&out[(size_t)n * C + 8 * lane] = o;
        }
    } else {
        if(active && half == 0){
            #pragma unroll
            for(int j = 0; j < 8; j++) sbuf[wave][8 * hl + j] = acc[j];
        }
        __syncthreads();
        float* out = (float*)outv;
        float4 o = {0,0,0,0};
        if(lane < 10){
            const int c = 4 * lane;
            #pragma unroll
            for(int h = 0; h < 4; h++){
                o.x += sbuf[wave][h * 40 + c + 0];
                o.y += sbuf[wave][h * 40 + c + 1];
                o.z += sbuf[wave][h * 40 + c + 2];
                o.w += sbuf[wave][h * 40 + c + 3];
            }
            const float4 b4 = *(const float4*)&bias[c];
            o.x = fmaxf(o.x * 0.25f + b4.x, 0.f);
            o.y = fmaxf(o.y * 0.25f + b4.y, 0.f);
            o.z = fmaxf(o.z * 0.25f + b4.z, 0.f);
            o.w = fmaxf(o.w * 0.25f + b4.w, 0.f);
        }
        float lm = (lane < 10) ? fmaxf(fmaxf(o.x, o.y), fmaxf(o.z, o.w)) : -INFINITY;
        #pragma unroll
        for(int off = 8; off; off >>= 1) lm = fmaxf(lm, __shfl_xor(lm, off));
        float se = 0.f;
        if(lane < 10) se = __expf(o.x-lm) + __expf(o.y-lm) + __expf(o.z-lm) + __expf(o.w-lm);
        #pragma unroll
        for(int off = 8; off; off >>= 1) se += __shfl_xor(se, off);
        const float logZ = lm + logf(se);
        if(lane < 10){
            float4 r = {o.x - logZ, o.y - logZ, o.z - logZ, o.w - logZ};
            *(float4*)&out[(size_t)n * 40 + 4 * lane] = r;
        }
    }
}

// ---------------- driver ----------------
extern "C" void kernel_launch(void* const* d_in, const int* in_sizes, int n_in,
                              void* d_out, int out_size, void* d_ws, size_t ws_size,
                              hipStream_t stream){
    const int N = NNODES;
    const int E = in_sizes[1] / 2;

    const float* x   = (const float*)d_in[0];
    const float* W1  = (const float*)d_in[2];
    const float* as1 = (const float*)d_in[3];
    const float* ad1 = (const float*)d_in[4];
    const float* b1  = (const float*)d_in[5];
    const float* W2  = (const float*)d_in[6];
    const float* as2 = (const float*)d_in[7];
    const float* ad2 = (const float*)d_in[8];
    const float* b2  = (const float*)d_in[9];
    const float* W3  = (const float*)d_in[10];
    const float* as3 = (const float*)d_in[11];
    const float* ad3 = (const float*)d_in[12];
    const float* b3  = (const float*)d_in[13];

    char* ws = (char*)d_ws;
    size_t off = 0;
    auto alloc = [&](size_t bytes) -> void* {
        void* p = ws + off;
        off = (off + bytes + 255) & ~(size_t)255;
        return p;
    };
    int*   flag    = (int*)  alloc(4);
    int*   e32     = (int*)  alloc((size_t)2 * E * 4);
    int*   row_ptr = (int*)  alloc((size_t)(N + 1) * 4);
    int*   colv    = (int*)  alloc((size_t)E * 4);
    int*   cursor  = (int*)  alloc((size_t)N * 4);
    int*   deg     = (int*)  alloc((size_t)N * 4);
    int*   excl    = (int*)  alloc((size_t)N * 4);
    int*   bsum    = (int*)  alloc(128 * 4);
    unsigned short* xp  = (unsigned short*)alloc((size_t)N * 256 * 2);
    unsigned short* xbf = (unsigned short*)alloc((size_t)N * 128 * 2);
    unsigned short* W1t = (unsigned short*)alloc((size_t)264 * 128 * 2);
    unsigned short* W2t = (unsigned short*)alloc((size_t)264 * 64 * 2);
    unsigned short* W3t = (unsigned short*)alloc((size_t)168 * 64 * 2);
    f32x2* eav     = (f32x2*)alloc((size_t)N * 4 * 8);
    f32x2* edv     = (f32x2*)alloc((size_t)N * 4 * 8);
    unsigned short* h = (unsigned short*)alloc((size_t)N * 64 * 2);
    (void)ws_size;

    hipMemsetAsync(deg, 0, (size_t)N * 4, stream);
    detect_kernel<<<1, 64, 0, stream>>>((const unsigned long long*)d_in[1], flag);
    convert_kernel<<<(2 * E + 255) / 256, 256, 0, stream>>>(d_in[1], flag, e32, deg, 2 * E, E);
    const int* srcv = e32;
    const int* dstv = e32 + E;

    f2bf_kernel<<<(N * 128 / 4 + 255) / 256, 256, 0, stream>>>(x, xbf, N * 128 / 4);
    const int prepTotal = 264 * 128 + 264 * 64 + 168 * 64;   // 61440
    prep_kernel<<<(prepTotal + 255) / 256, 256, 0, stream>>>(W1, as1, ad1, W2, as2, ad2,
                                                             W3, as3, ad3, W1t, W2t, W3t);

    const int nbScan = (N + 511) / 512;
    scan1_kernel<<<nbScan, 512, 0, stream>>>(deg, excl, bsum, N);
    scan2_kernel<<<1, 128, 0, stream>>>(bsum, nbScan);
    scan3_kernel<<<(N + 255) / 256, 256, 0, stream>>>(excl, bsum, row_ptr, cursor, N, E);
    scatter_kernel<<<(E + 255) / 256, 256, 0, stream>>>(srcv, dstv, cursor, colv, E);

    const int nodeBlocks = N / 4;              // 12500
    const int mBlocks = (N + 63) / 64;         // 782

    // layer 1: 128 -> 64 (HC=256)
    mfma_gemm_kernel<128, 256><<<mBlocks, 256, 0, stream>>>(xbf, W1t, xp, eav, edv, N);
    gather_kernel<64, false><<<nodeBlocks, 256, 0, stream>>>(xp, row_ptr, colv, eav, edv, b1, h);

    // layer 2: 64 -> 64 (HC=256)
    mfma_gemm_kernel<64, 256><<<mBlocks, 256, 0, stream>>>(h, W2t, xp, eav, edv, N);
    gather_kernel<64, false><<<nodeBlocks, 256, 0, stream>>>(xp, row_ptr, colv, eav, edv, b2, h);

    // layer 3: 64 -> 40 (HC=160) + fused log_softmax
    mfma_gemm_kernel<64, 160><<<mBlocks, 256, 0, stream>>>(h, W3t, xp, eav, edv, N);
    gather_kernel<40, true><<<nodeBlocks, 256, 0, stream>>>(xp, row_ptr, colv, eav, edv, b3, (float*)d_out);
}

// Round 8
// 462.921 us; speedup vs baseline: 1.0438x; 1.0438x over previous
//
#include <hip/hip_runtime.h>
#include <math.h>

#define NNODES 50000
#define NEG_SLOPE 0.2f

typedef unsigned short ushort8v __attribute__((ext_vector_type(8)));
typedef unsigned short ushort4v __attribute__((ext_vector_type(4)));
typedef short short8v __attribute__((ext_vector_type(8)));
typedef float f32x4 __attribute__((ext_vector_type(4)));
typedef float f32x2 __attribute__((ext_vector_type(2)));

__device__ __forceinline__ float bf2f(unsigned short u){ return __uint_as_float(((unsigned)u) << 16); }
__device__ __forceinline__ unsigned short f2bf(float f){
    unsigned u = __float_as_uint(f);
    u += 0x7fff + ((u >> 16) & 1);   // RNE; inputs finite
    return (unsigned short)(u >> 16);
}

// ---------------- init: edge dtype detect (block 0) + zero deg (all blocks) ----------------
__global__ void init_kernel(const unsigned long long* __restrict__ e, int* __restrict__ flag,
                            int* __restrict__ deg, int N){
    if(blockIdx.x == 0 && threadIdx.x < 64){
        const unsigned long long v = e[threadIdx.x];
        const unsigned long long mask = __ballot(v >= (1ULL << 32));
        if(threadIdx.x == 0) *flag = (mask == 0ULL) ? 1 : 0;
    }
    for(int i = blockIdx.x * blockDim.x + threadIdx.x; i < N; i += gridDim.x * blockDim.x)
        deg[i] = 0;
}

// ---------------- histogram straight off the raw edge buffer ----------------
__global__ void hist_kernel(const void* __restrict__ e, const int* __restrict__ flag,
                            int* __restrict__ deg, int E){
    const int i = blockIdx.x * blockDim.x + threadIdx.x;
    if(i < E){
        const int d = (*flag) ? (int)((const long long*)e)[E + i] : ((const int*)e)[E + i];
        atomicAdd(&deg[d], 1);
    }
}

// ---------------- CSR build (hierarchical scan) ----------------
__global__ __launch_bounds__(512) void scan1_kernel(const int* __restrict__ deg,
                                                    int* __restrict__ excl,
                                                    int* __restrict__ bsum, int n){
    __shared__ int sh[512];
    const int t = threadIdx.x;
    const int gid = blockIdx.x * 512 + t;
    const int v = (gid < n) ? deg[gid] : 0;
    sh[t] = v;
    __syncthreads();
    for(int off = 1; off < 512; off <<= 1){
        const int add = (t >= off) ? sh[t - off] : 0;
        __syncthreads();
        sh[t] += add;
        __syncthreads();
    }
    if(gid < n) excl[gid] = sh[t] - v;
    if(t == 511) bsum[blockIdx.x] = sh[511];
}

__global__ __launch_bounds__(128) void scan2_kernel(int* __restrict__ bsum, int nb){
    __shared__ int sh[128];
    const int t = threadIdx.x;
    const int v = (t < nb) ? bsum[t] : 0;
    sh[t] = v;
    __syncthreads();
    for(int off = 1; off < 128; off <<= 1){
        const int add = (t >= off) ? sh[t - off] : 0;
        __syncthreads();
        sh[t] += add;
        __syncthreads();
    }
    if(t < nb) bsum[t] = sh[t] - v;
}

__global__ void scan3_kernel(const int* __restrict__ excl, const int* __restrict__ bsum,
                             int* __restrict__ row_ptr, int* __restrict__ cursor,
                             int n, int E){
    const int gid = blockIdx.x * blockDim.x + threadIdx.x;
    if(gid < n){
        const int r = excl[gid] + bsum[gid >> 9];
        row_ptr[gid] = r;
        cursor[gid] = r;
    }
    if(gid == 0) row_ptr[n] = E;
}

// ---------------- scatter straight off the raw edge buffer ----------------
__global__ void scatter_kernel(const void* __restrict__ e, const int* __restrict__ flag,
                               int* __restrict__ cursor, int* __restrict__ col, int E){
    const int i = blockIdx.x * blockDim.x + threadIdx.x;
    if(i < E){
        int s, d;
        if(*flag){ s = (int)((const long long*)e)[i]; d = (int)((const long long*)e)[E + i]; }
        else     { s = ((const int*)e)[i];            d = ((const int*)e)[E + i]; }
        const int pos = atomicAdd(&cursor[d], 1);
        col[pos] = s;
    }
}

// ---------------- fused prep: x->bf16 and Wt[NC+8][K] = [W^T ; ws ; wd] bf16 ----------------
// Appending ws=W@a_s / wd=W@a_d lets the GEMM emit aS/aD directly (alpha linear in x).
__device__ __forceinline__ void emit_wt(const float* __restrict__ W, const float* __restrict__ a_s,
                                        const float* __restrict__ a_d, unsigned short* __restrict__ Wt,
                                        int K, int NC, int C, int id){
    const int n = id / K, k = id - n * K;
    float v;
    if(n < NC){
        v = W[(size_t)k * NC + n];
    } else {
        const int h = n - NC;
        const int hh = h & 3;
        const float* av = (h < 4) ? a_s : a_d;
        v = 0.f;
        for(int c = 0; c < C; c++) v += W[(size_t)k * NC + hh * C + c] * av[hh * C + c];
    }
    Wt[(size_t)n * K + k] = f2bf(v);
}

__global__ void prep_kernel(const float* __restrict__ x, unsigned short* __restrict__ xbf, int X4,
                            const float* __restrict__ W1, const float* __restrict__ as1, const float* __restrict__ ad1,
                            const float* __restrict__ W2, const float* __restrict__ as2, const float* __restrict__ ad2,
                            const float* __restrict__ W3, const float* __restrict__ as3, const float* __restrict__ ad3,
                            unsigned short* __restrict__ W1t, unsigned short* __restrict__ W2t,
                            unsigned short* __restrict__ W3t){
    int id = blockIdx.x * blockDim.x + threadIdx.x;
    if(id < X4){
        const float4 v = *(const float4*)&x[(size_t)id * 4];
        ushort4v o;
        o[0] = f2bf(v.x); o[1] = f2bf(v.y); o[2] = f2bf(v.z); o[3] = f2bf(v.w);
        *(ushort4v*)&xbf[(size_t)id * 4] = o;
        return;
    }
    id -= X4;
    if(id < 264 * 128){ emit_wt(W1, as1, ad1, W1t, 128, 256, 64, id); return; }
    id -= 264 * 128;
    if(id < 264 * 64){ emit_wt(W2, as2, ad2, W2t, 64, 256, 64, id); return; }
    id -= 264 * 64;
    if(id < 168 * 64){ emit_wt(W3, as3, ad3, W3t, 64, 160, 40, id); }
}

// ---------------- MFMA bf16 GEMM (2D grid) + fused alpha/exp epilogue ----------------
// grid (M/64, ceil(NC/64)); block computes 4 column tiles; y==0 blocks also
// compute the 8 alpha columns (rows NC..NC+7 of Bt) and store pre-exponentiated
// ea=(exp(aS),exp(.2 aS)), ed likewise.
template<int K, int NC>
__global__ __launch_bounds__(256) void mfma_gemm_kernel(const unsigned short* __restrict__ A,
                                                        const unsigned short* __restrict__ Bt,
                                                        unsigned short* __restrict__ C,
                                                        f32x2* __restrict__ ea,
                                                        f32x2* __restrict__ ed,
                                                        int M){
    const int lane = threadIdx.x & 63;
    const int wave = threadIdx.x >> 6;
    const int quad = lane >> 4;
    const int l16 = lane & 15;
    const int bm = blockIdx.x * 64;
    const int bn = blockIdx.y * 64;
    const int nt = (blockIdx.y == 0) ? 5 : 4;
    const int m = min(bm + wave * 16 + l16, M - 1);
    const size_t arow = (size_t)m * K;

    f32x4 acc[5];
    #pragma unroll
    for(int t = 0; t < 5; t++) acc[t] = (f32x4){0,0,0,0};
    int cn[5];
    #pragma unroll
    for(int t = 0; t < 4; t++) cn[t] = min(bn + t * 16 + l16, NC - 1);
    cn[4] = NC + min(l16, 7);

    for(int k0 = 0; k0 < K; k0 += 32){
        const short8v a = *(const short8v*)&A[arow + k0 + quad * 8];
        #pragma unroll
        for(int t = 0; t < 5; t++){
            if(t < nt){
                const short8v b = *(const short8v*)&Bt[(size_t)cn[t] * K + k0 + quad * 8];
                acc[t] = __builtin_amdgcn_mfma_f32_16x16x32_bf16(a, b, acc[t], 0, 0, 0);
            }
        }
    }
    const int rbase = bm + wave * 16 + quad * 4;
    #pragma unroll
    for(int t = 0; t < 4; t++){
        const int c = bn + t * 16 + l16;
        if(c < NC){
            #pragma unroll
            for(int r = 0; r < 4; r++){
                const int row = rbase + r;
                if(row < M) C[(size_t)row * NC + c] = f2bf(acc[t][r]);
            }
        }
    }
    if(blockIdx.y == 0 && l16 < 8){
        const int h = l16 & 3;
        f32x2* dst = (l16 < 4) ? ea : ed;
        #pragma unroll
        for(int r = 0; r < 4; r++){
            const int row = rbase + r;
            if(row < M){
                const float v = acc[4][r];
                f32x2 e2 = {__expf(v), __expf(NEG_SLOPE * v)};
                dst[(size_t)row * 4 + h] = e2;
            }
        }
    }
}

// ---------------- fused softmax + weighted gather, 8 edges in flight ----------------
// w = exp(lrelu(aS+aD)) = max(exp(aS)exp(aD), exp(.2aS)exp(.2aD)); no transcendental
// in the loop. bf16 pairs unpacked shift/mask into packed f32x2 FMA; denom in-pass.
template<int C, bool FINAL>
__global__ __launch_bounds__(256) void gather_kernel(const unsigned short* __restrict__ xp,
                                                     const int* __restrict__ row_ptr,
                                                     const int* __restrict__ col,
                                                     const f32x2* __restrict__ ea,
                                                     const f32x2* __restrict__ ed,
                                                     const float* __restrict__ bias,
                                                     void* __restrict__ outv){
    constexpr int HC = 4 * C;
    constexpr int LPE = HC / 8;     // lanes per edge: 32 or 20
    __shared__ float sbuf[4][FINAL ? HC : 1];
    const int lane = threadIdx.x & 63;
    const int wave = threadIdx.x >> 6;
    const int n = blockIdx.x * 4 + wave;
    const int half = lane >> 5;
    const int hl = lane & 31;
    const bool active = hl < LPE;
    const int head = min((8 * hl) / C, 3);
    const int rs = row_ptr[n], re = row_ptr[n + 1];
    const int T = re - rs + 1;      // edges + virtual self loop
    const f32x2 edh = ed[(size_t)n * 4 + head];
    const unsigned short* xpl = xp + 8 * hl;

    f32x2 acc2[4] = {{0,0},{0,0},{0,0},{0,0}};
    float denom = 0.f;
    int k = 0;
    for(; k + 8 <= T; k += 8){
        const int e0 = rs + k + half, e1 = e0 + 2, e2 = e0 + 4, e3 = e0 + 6;
        const int s0 = (e0 < re) ? col[e0] : n;
        const int s1 = (e1 < re) ? col[e1] : n;
        const int s2 = (e2 < re) ? col[e2] : n;
        const int s3 = (e3 < re) ? col[e3] : n;
        const f32x2 a0 = ea[(size_t)s0 * 4 + head];
        const f32x2 a1 = ea[(size_t)s1 * 4 + head];
        const f32x2 a2 = ea[(size_t)s2 * 4 + head];
        const f32x2 a3 = ea[(size_t)s3 * 4 + head];
        const float w0 = fmaxf(a0[0] * edh[0], a0[1] * edh[1]);
        const float w1 = fmaxf(a1[0] * edh[0], a1[1] * edh[1]);
        const float w2 = fmaxf(a2[0] * edh[0], a2[1] * edh[1]);
        const float w3 = fmaxf(a3[0] * edh[0], a3[1] * edh[1]);
        denom += (w0 + w1) + (w2 + w3);
        if(active){
            const uint4 u0 = *(const uint4*)&xpl[(size_t)s0 * HC];
            const uint4 u1 = *(const uint4*)&xpl[(size_t)s1 * HC];
            const uint4 u2 = *(const uint4*)&xpl[(size_t)s2 * HC];
            const uint4 u3 = *(const uint4*)&xpl[(size_t)s3 * HC];
            const f32x2 W0 = {w0, w0}, W1 = {w1, w1}, W2 = {w2, w2}, W3 = {w3, w3};
            acc2[0] += W0 * (f32x2){__uint_as_float(u0.x << 16), __uint_as_float(u0.x & 0xffff0000u)};
            acc2[1] += W0 * (f32x2){__uint_as_float(u0.y << 16), __uint_as_float(u0.y & 0xffff0000u)};
            acc2[2] += W0 * (f32x2){__uint_as_float(u0.z << 16), __uint_as_float(u0.z & 0xffff0000u)};
            acc2[3] += W0 * (f32x2){__uint_as_float(u0.w << 16), __uint_as_float(u0.w & 0xffff0000u)};
            acc2[0] += W1 * (f32x2){__uint_as_float(u1.x << 16), __uint_as_float(u1.x & 0xffff0000u)};
            acc2[1] += W1 * (f32x2){__uint_as_float(u1.y << 16), __uint_as_float(u1.y & 0xffff0000u)};
            acc2[2] += W1 * (f32x2){__uint_as_float(u1.z << 16), __uint_as_float(u1.z & 0xffff0000u)};
            acc2[3] += W1 * (f32x2){__uint_as_float(u1.w << 16), __uint_as_float(u1.w & 0xffff0000u)};
            acc2[0] += W2 * (f32x2){__uint_as_float(u2.x << 16), __uint_as_float(u2.x & 0xffff0000u)};
            acc2[1] += W2 * (f32x2){__uint_as_float(u2.y << 16), __uint_as_float(u2.y & 0xffff0000u)};
            acc2[2] += W2 * (f32x2){__uint_as_float(u2.z << 16), __uint_as_float(u2.z & 0xffff0000u)};
            acc2[3] += W2 * (f32x2){__uint_as_float(u2.w << 16), __uint_as_float(u2.w & 0xffff0000u)};
            acc2[0] += W3 * (f32x2){__uint_as_float(u3.x << 16), __uint_as_float(u3.x & 0xffff0000u)};
            acc2[1] += W3 * (f32x2){__uint_as_float(u3.y << 16), __uint_as_float(u3.y & 0xffff0000u)};
            acc2[2] += W3 * (f32x2){__uint_as_float(u3.z << 16), __uint_as_float(u3.z & 0xffff0000u)};
            acc2[3] += W3 * (f32x2){__uint_as_float(u3.w << 16), __uint_as_float(u3.w & 0xffff0000u)};
        }
    }
    for(; k + 2 <= T; k += 2){
        const int e = rs + k + half;
        const int s = (e < re) ? col[e] : n;
        const f32x2 a2 = ea[(size_t)s * 4 + head];
        const float wh = fmaxf(a2[0] * edh[0], a2[1] * edh[1]);
        denom += wh;
        if(active){
            const uint4 u = *(const uint4*)&xpl[(size_t)s * HC];
            const f32x2 w2 = {wh, wh};
            acc2[0] += w2 * (f32x2){__uint_as_float(u.x << 16), __uint_as_float(u.x & 0xffff0000u)};
            acc2[1] += w2 * (f32x2){__uint_as_float(u.y << 16), __uint_as_float(u.y & 0xffff0000u)};
            acc2[2] += w2 * (f32x2){__uint_as_float(u.z << 16), __uint_as_float(u.z & 0xffff0000u)};
            acc2[3] += w2 * (f32x2){__uint_as_float(u.w << 16), __uint_as_float(u.w & 0xffff0000u)};
        }
    }
    if(k < T && half == 0){
        const int e = rs + k;
        const int s = (e < re) ? col[e] : n;
        const f32x2 a2 = ea[(size_t)s * 4 + head];
        const float wh = fmaxf(a2[0] * edh[0], a2[1] * edh[1]);
        denom += wh;
        if(active){
            const uint4 u = *(const uint4*)&xpl[(size_t)s * HC];
            const f32x2 w2 = {wh, wh};
            acc2[0] += w2 * (f32x2){__uint_as_float(u.x << 16), __uint_as_float(u.x & 0xffff0000u)};
            acc2[1] += w2 * (f32x2){__uint_as_float(u.y << 16), __uint_as_float(u.y & 0xffff0000u)};
            acc2[2] += w2 * (f32x2){__uint_as_float(u.z << 16), __uint_as_float(u.z & 0xffff0000u)};
            acc2[3] += w2 * (f32x2){__uint_as_float(u.w << 16), __uint_as_float(u.w & 0xffff0000u)};
        }
    }
    // merge halves (xor-32 partner has same hl -> same head)
    #pragma unroll
    for(int p = 0; p < 4; p++){
        acc2[p][0] += __shfl_xor(acc2[p][0], 32);
        acc2[p][1] += __shfl_xor(acc2[p][1], 32);
    }
    denom += __shfl_xor(denom, 32);
    const float ih = 1.f / denom;
    float acc[8];
    #pragma unroll
    for(int p = 0; p < 4; p++){ acc[2*p] = acc2[p][0] * ih; acc[2*p+1] = acc2[p][1] * ih; }

    if(!FINAL){
        #pragma unroll
        for(int j = 0; j < 8; j++){
            acc[j] += __shfl_xor(acc[j], 8);
            acc[j] += __shfl_xor(acc[j], 16);
        }
        if(lane < 8){
            unsigned short* out = (unsigned short*)outv;
            ushort8v o;
            #pragma unroll
            for(int j = 0; j < 8; j++)
                o[j] = f2bf(fmaxf(acc[j] * 0.25f + bias[8 * lane + j], 0.f));
            *(ushort8v*)&out[(size_t)n * C + 8 * lane] = o;
        }
    } else {
        if(active && half == 0){
            #pragma unroll
            for(int j = 0; j < 8; j++) sbuf[wave][8 * hl + j] = acc[j];
        }
        __syncthreads();
        float* out = (float*)outv;
        float4 o = {0,0,0,0};
        if(lane < 10){
            const int c = 4 * lane;
            #pragma unroll
            for(int h = 0; h < 4; h++){
                o.x += sbuf[wave][h * 40 + c + 0];
                o.y += sbuf[wave][h * 40 + c + 1];
                o.z += sbuf[wave][h * 40 + c + 2];
                o.w += sbuf[wave][h * 40 + c + 3];
            }
            const float4 b4 = *(const float4*)&bias[c];
            o.x = fmaxf(o.x * 0.25f + b4.x, 0.f);
            o.y = fmaxf(o.y * 0.25f + b4.y, 0.f);
            o.z = fmaxf(o.z * 0.25f + b4.z, 0.f);
            o.w = fmaxf(o.w * 0.25f + b4.w, 0.f);
        }
        float lm = (lane < 10) ? fmaxf(fmaxf(o.x, o.y), fmaxf(o.z, o.w)) : -INFINITY;
        #pragma unroll
        for(int off = 8; off; off >>= 1) lm = fmaxf(lm, __shfl_xor(lm, off));
        float se = 0.f;
        if(lane < 10) se = __expf(o.x-lm) + __expf(o.y-lm) + __expf(o.z-lm) + __expf(o.w-lm);
        #pragma unroll
        for(int off = 8; off; off >>= 1) se += __shfl_xor(se, off);
        const float logZ = lm + logf(se);
        if(lane < 10){
            float4 r = {o.x - logZ, o.y - logZ, o.z - logZ, o.w - logZ};
            *(float4*)&out[(size_t)n * 40 + 4 * lane] = r;
        }
    }
}

// ---------------- driver ----------------
extern "C" void kernel_launch(void* const* d_in, const int* in_sizes, int n_in,
                              void* d_out, int out_size, void* d_ws, size_t ws_size,
                              hipStream_t stream){
    const int N = NNODES;
    const int E = in_sizes[1] / 2;

    const float* x   = (const float*)d_in[0];
    const float* W1  = (const float*)d_in[2];
    const float* as1 = (const float*)d_in[3];
    const float* ad1 = (const float*)d_in[4];
    const float* b1  = (const float*)d_in[5];
    const float* W2  = (const float*)d_in[6];
    const float* as2 = (const float*)d_in[7];
    const float* ad2 = (const float*)d_in[8];
    const float* b2  = (const float*)d_in[9];
    const float* W3  = (const float*)d_in[10];
    const float* as3 = (const float*)d_in[11];
    const float* ad3 = (const float*)d_in[12];
    const float* b3  = (const float*)d_in[13];

    char* ws = (char*)d_ws;
    size_t off = 0;
    auto alloc = [&](size_t bytes) -> void* {
        void* p = ws + off;
        off = (off + bytes + 255) & ~(size_t)255;
        return p;
    };
    int*   flag    = (int*)  alloc(4);
    int*   row_ptr = (int*)  alloc((size_t)(N + 1) * 4);
    int*   colv    = (int*)  alloc((size_t)E * 4);
    int*   cursor  = (int*)  alloc((size_t)N * 4);
    int*   deg     = (int*)  alloc((size_t)N * 4);
    int*   excl    = (int*)  alloc((size_t)N * 4);
    int*   bsum    = (int*)  alloc(128 * 4);
    unsigned short* xp  = (unsigned short*)alloc((size_t)N * 256 * 2);
    unsigned short* xbf = (unsigned short*)alloc((size_t)N * 128 * 2);
    unsigned short* W1t = (unsigned short*)alloc((size_t)264 * 128 * 2);
    unsigned short* W2t = (unsigned short*)alloc((size_t)264 * 64 * 2);
    unsigned short* W3t = (unsigned short*)alloc((size_t)168 * 64 * 2);
    f32x2* eav     = (f32x2*)alloc((size_t)N * 4 * 8);
    f32x2* edv     = (f32x2*)alloc((size_t)N * 4 * 8);
    unsigned short* h = (unsigned short*)alloc((size_t)N * 64 * 2);
    (void)ws_size;

    const void* eraw = d_in[1];

    init_kernel<<<(N + 255) / 256, 256, 0, stream>>>((const unsigned long long*)eraw, flag, deg, N);
    hist_kernel<<<(E + 255) / 256, 256, 0, stream>>>(eraw, flag, deg, E);

    const int X4 = N * 128 / 4;   // 1,600,000 float4 groups of x
    const int prepTotal = X4 + 264 * 128 + 264 * 64 + 168 * 64;
    prep_kernel<<<(prepTotal + 255) / 256, 256, 0, stream>>>(x, xbf, X4,
                                                             W1, as1, ad1, W2, as2, ad2,
                                                             W3, as3, ad3, W1t, W2t, W3t);

    const int nbScan = (N + 511) / 512;
    scan1_kernel<<<nbScan, 512, 0, stream>>>(deg, excl, bsum, N);
    scan2_kernel<<<1, 128, 0, stream>>>(bsum, nbScan);
    scan3_kernel<<<(N + 255) / 256, 256, 0, stream>>>(excl, bsum, row_ptr, cursor, N, E);
    scatter_kernel<<<(E + 255) / 256, 256, 0, stream>>>(eraw, flag, cursor, colv, E);

    const int nodeBlocks = N / 4;              // 12500
    const int mBlocks = (N + 63) / 64;         // 782

    // layer 1: 128 -> 64 (HC=256)
    mfma_gemm_kernel<128, 256><<<dim3(mBlocks, 4), 256, 0, stream>>>(xbf, W1t, xp, eav, edv, N);
    gather_kernel<64, false><<<nodeBlocks, 256, 0, stream>>>(xp, row_ptr, colv, eav, edv, b1, h);

    // layer 2: 64 -> 64 (HC=256)
    mfma_gemm_kernel<64, 256><<<dim3(mBlocks, 4), 256, 0, stream>>>(h, W2t, xp, eav, edv, N);
    gather_kernel<64, false><<<nodeBlocks, 256, 0, stream>>>(xp, row_ptr, colv, eav, edv, b2, h);

    // layer 3: 64 -> 40 (HC=160) + fused log_softmax
    mfma_gemm_kernel<64, 160><<<dim3(mBlocks, 3), 256, 0, stream>>>(h, W3t, xp, eav, edv, N);
    gather_kernel<40, true><<<nodeBlocks, 256, 0, stream>>>(xp, row_ptr, colv, eav, edv, b3, (float*)d_out);
}

// Round 9
// 436.305 us; speedup vs baseline: 1.1074x; 1.0610x over previous
//
#include <hip/hip_runtime.h>
#include <math.h>

#define NNODES 50000
#define NEG_SLOPE 0.2f

typedef unsigned short ushort8v __attribute__((ext_vector_type(8)));
typedef unsigned short ushort4v __attribute__((ext_vector_type(4)));
typedef short short8v __attribute__((ext_vector_type(8)));
typedef float f32x4 __attribute__((ext_vector_type(4)));
typedef float f32x2 __attribute__((ext_vector_type(2)));

__device__ __forceinline__ unsigned short f2bf(float f){
    unsigned u = __float_as_uint(f);
    u += 0x7fff + ((u >> 16) & 1);   // RNE; inputs finite
    return (unsigned short)(u >> 16);
}

// ---------------- init: edge dtype detect (block 0) + zero deg ----------------
__global__ void init_kernel(const unsigned long long* __restrict__ e, int* __restrict__ flag,
                            int* __restrict__ deg, int N){
    if(blockIdx.x == 0 && threadIdx.x < 64){
        const unsigned long long v = e[threadIdx.x];
        const unsigned long long mask = __ballot(v >= (1ULL << 32));
        if(threadIdx.x == 0) *flag = (mask == 0ULL) ? 1 : 0;
    }
    for(int i = blockIdx.x * blockDim.x + threadIdx.x; i < N; i += gridDim.x * blockDim.x)
        deg[i] = 0;
}

// ---------------- histogram off the raw edge buffer ----------------
__global__ void hist_kernel(const void* __restrict__ e, const int* __restrict__ flag,
                            int* __restrict__ deg, int E){
    const int i = blockIdx.x * blockDim.x + threadIdx.x;
    if(i < E){
        const int d = (*flag) ? (int)((const long long*)e)[E + i] : ((const int*)e)[E + i];
        atomicAdd(&deg[d], 1);
    }
}

// ---------------- CSR build (hierarchical scan) ----------------
__global__ __launch_bounds__(512) void scan1_kernel(const int* __restrict__ deg,
                                                    int* __restrict__ excl,
                                                    int* __restrict__ bsum, int n){
    __shared__ int sh[512];
    const int t = threadIdx.x;
    const int gid = blockIdx.x * 512 + t;
    const int v = (gid < n) ? deg[gid] : 0;
    sh[t] = v;
    __syncthreads();
    for(int off = 1; off < 512; off <<= 1){
        const int add = (t >= off) ? sh[t - off] : 0;
        __syncthreads();
        sh[t] += add;
        __syncthreads();
    }
    if(gid < n) excl[gid] = sh[t] - v;
    if(t == 511) bsum[blockIdx.x] = sh[511];
}

__global__ __launch_bounds__(128) void scan2_kernel(int* __restrict__ bsum, int nb){
    __shared__ int sh[128];
    const int t = threadIdx.x;
    const int v = (t < nb) ? bsum[t] : 0;
    sh[t] = v;
    __syncthreads();
    for(int off = 1; off < 128; off <<= 1){
        const int add = (t >= off) ? sh[t - off] : 0;
        __syncthreads();
        sh[t] += add;
        __syncthreads();
    }
    if(t < nb) bsum[t] = sh[t] - v;
}

__global__ void scan3_kernel(const int* __restrict__ excl, const int* __restrict__ bsum,
                             int* __restrict__ row_ptr, int* __restrict__ cursor,
                             int n, int E){
    const int gid = blockIdx.x * blockDim.x + threadIdx.x;
    if(gid < n){
        const int r = excl[gid] + bsum[gid >> 9];
        row_ptr[gid] = r;
        cursor[gid] = r;
    }
    if(gid == 0) row_ptr[n] = E;
}

__global__ void scatter_kernel(const void* __restrict__ e, const int* __restrict__ flag,
                               int* __restrict__ cursor, int* __restrict__ col, int E){
    const int i = blockIdx.x * blockDim.x + threadIdx.x;
    if(i < E){
        int s, d;
        if(*flag){ s = (int)((const long long*)e)[i]; d = (int)((const long long*)e)[E + i]; }
        else     { s = ((const int*)e)[i];            d = ((const int*)e)[E + i]; }
        const int pos = atomicAdd(&cursor[d], 1);
        col[pos] = s;
    }
}

// ---------------- prep: xbf + Wa (alpha proj) + Wcat (per-head stacked W^T) ----------------
// Wa[n][k], n<8: row h<4 = W@a_s head h; h>=4 = W@a_d; rows 8..15 zero (MFMA pad).
__device__ __forceinline__ void emit_wa(const float* __restrict__ W, const float* __restrict__ a_s,
                                        const float* __restrict__ a_d, unsigned short* __restrict__ Wt,
                                        int Kin, int C, int id){
    const int n = id / Kin, k = id - n * Kin;
    float v = 0.f;
    if(n < 8){
        const int hh = n & 3;
        const float* av = (n < 4) ? a_s : a_d;
        for(int c = 0; c < C; c++) v += W[(size_t)k * (4 * C) + hh * C + c] * av[hh * C + c];
    }
    Wt[id] = f2bf(v);
}

// Wcat[c][h*Kin+k] = W[k][h*C+c] * 0.25 (head-mean folded); rows c>=C zero-padded.
__device__ __forceinline__ void emit_wc(const float* __restrict__ W, unsigned short* __restrict__ Wt,
                                        int Kin, int C, int id){
    const int c = id / (4 * Kin);
    const int hk = id - c * (4 * Kin);
    const int h = hk / Kin, k = hk - h * Kin;
    const float v = (c < C) ? W[(size_t)k * (4 * C) + h * C + c] * 0.25f : 0.f;
    Wt[id] = f2bf(v);
}

__global__ void prep_kernel(const float* __restrict__ x, unsigned short* __restrict__ xbf, int X4,
                            const float* __restrict__ W1, const float* __restrict__ as1, const float* __restrict__ ad1,
                            const float* __restrict__ W2, const float* __restrict__ as2, const float* __restrict__ ad2,
                            const float* __restrict__ W3, const float* __restrict__ as3, const float* __restrict__ ad3,
                            unsigned short* __restrict__ Wa1, unsigned short* __restrict__ Wa2,
                            unsigned short* __restrict__ Wa3, unsigned short* __restrict__ Wc1,
                            unsigned short* __restrict__ Wc2, unsigned short* __restrict__ Wc3){
    int id = blockIdx.x * blockDim.x + threadIdx.x;
    if(id < X4){
        const float4 v = *(const float4*)&x[(size_t)id * 4];
        ushort4v o;
        o[0] = f2bf(v.x); o[1] = f2bf(v.y); o[2] = f2bf(v.z); o[3] = f2bf(v.w);
        *(ushort4v*)&xbf[(size_t)id * 4] = o;
        return;
    }
    id -= X4;
    if(id < 16 * 128){ emit_wa(W1, as1, ad1, Wa1, 128, 64, id); return; }
    id -= 16 * 128;
    if(id < 16 * 64){ emit_wa(W2, as2, ad2, Wa2, 64, 64, id); return; }
    id -= 16 * 64;
    if(id < 16 * 64){ emit_wa(W3, as3, ad3, Wa3, 64, 40, id); return; }
    id -= 16 * 64;
    if(id < 64 * 512){ emit_wc(W1, Wc1, 128, 64, id); return; }
    id -= 64 * 512;
    if(id < 64 * 256){ emit_wc(W2, Wc2, 64, 64, id); return; }
    id -= 64 * 256;
    if(id < 48 * 256){ emit_wc(W3, Wc3, 64, 40, id); }
}

// ---------------- alpha GEMM: ea/ed = exp(A @ Wa) (8 cols), pre-exponentiated ----------------
template<int K>
__global__ __launch_bounds__(256) void agemm_kernel(const unsigned short* __restrict__ A,
                                                    const unsigned short* __restrict__ Wa,
                                                    float* __restrict__ ea, float* __restrict__ ed,
                                                    int M){
    const int lane = threadIdx.x & 63;
    const int wave = threadIdx.x >> 6;
    const int quad = lane >> 4;
    const int l16 = lane & 15;
    const int bm = blockIdx.x * 64;
    const int m = min(bm + wave * 16 + l16, M - 1);
    f32x4 acc = {0,0,0,0};
    #pragma unroll
    for(int k0 = 0; k0 < K; k0 += 32){
        const short8v a = *(const short8v*)&A[(size_t)m * K + k0 + quad * 8];
        const short8v b = *(const short8v*)&Wa[(size_t)l16 * K + k0 + quad * 8];
        acc = __builtin_amdgcn_mfma_f32_16x16x32_bf16(a, b, acc, 0, 0, 0);
    }
    if(l16 < 8){
        const int h = l16 & 3;
        float* dst = (l16 < 4) ? ea : ed;
        const int rbase = bm + wave * 16 + quad * 4;
        #pragma unroll
        for(int r = 0; r < 4; r++){
            const int row = rbase + r;
            if(row < M){
                const float v = acc[r];
                *(f32x2*)&dst[(size_t)row * 8 + 2 * h] = (f32x2){__expf(v), __expf(NEG_SLOPE * v)};
            }
        }
    }
}

// ---------------- gather RAW features: g[n][h*K+k] = (1/denom_h) sum_s w_h(s) X[s][k] ----------------
// 16 lanes/edge (4 slots/wave), lane owns K/16 channels; row = 128/256 B per edge
// (vs 512 B of projected xp). w_h = max(ea_s[h]*ed_n[h]) pairs -- no transcendental.
template<int K>
__global__ __launch_bounds__(256) void gather_kernel(const unsigned short* __restrict__ X,
                                                     const int* __restrict__ row_ptr,
                                                     const int* __restrict__ col,
                                                     const float* __restrict__ ea,
                                                     const float* __restrict__ ed,
                                                     unsigned short* __restrict__ g){
    constexpr int CPL = K / 16;       // channels per lane: 4 or 8
    constexpr int PAIRS = CPL / 2;    // 2 or 4
    const int lane = threadIdx.x & 63;
    const int wave = threadIdx.x >> 6;
    const int n = blockIdx.x * 4 + wave;
    const int slot = lane >> 4;
    const int pos = lane & 15;
    const int rs = row_ptr[n], re = row_ptr[n + 1];
    const int T = re - rs + 1;        // edges + virtual self loop
    const float4 edA = *(const float4*)&ed[(size_t)n * 8];
    const float4 edB = *(const float4*)&ed[(size_t)n * 8 + 4];

    f32x2 acc[4][PAIRS];
    #pragma unroll
    for(int h = 0; h < 4; h++)
        #pragma unroll
        for(int p = 0; p < PAIRS; p++) acc[h][p] = (f32x2){0.f, 0.f};
    float dnm[4] = {0.f, 0.f, 0.f, 0.f};

    auto body = [&](int e){
        const int s = (e < re) ? col[e] : n;   // e==re => self loop (at most one slot)
        const float4 eaA = *(const float4*)&ea[(size_t)s * 8];
        const float4 eaB = *(const float4*)&ea[(size_t)s * 8 + 4];
        const float w0 = fmaxf(eaA.x * edA.x, eaA.y * edA.y);
        const float w1 = fmaxf(eaA.z * edA.z, eaA.w * edA.w);
        const float w2 = fmaxf(eaB.x * edB.x, eaB.y * edB.y);
        const float w3 = fmaxf(eaB.z * edB.z, eaB.w * edB.w);
        dnm[0] += w0; dnm[1] += w1; dnm[2] += w2; dnm[3] += w3;
        unsigned u[PAIRS];
        if constexpr(PAIRS == 2){
            const uint2 t2 = *(const uint2*)&X[(size_t)s * K + pos * CPL];
            u[0] = t2.x; u[1] = t2.y;
        } else {
            const uint4 t4 = *(const uint4*)&X[(size_t)s * K + pos * CPL];
            u[0] = t4.x; u[1] = t4.y; u[2] = t4.z; u[3] = t4.w;
        }
        #pragma unroll
        for(int p = 0; p < PAIRS; p++){
            const f32x2 v = {__uint_as_float(u[p] << 16), __uint_as_float(u[p] & 0xffff0000u)};
            acc[0][p] += (f32x2){w0, w0} * v;
            acc[1][p] += (f32x2){w1, w1} * v;
            acc[2][p] += (f32x2){w2, w2} * v;
            acc[3][p] += (f32x2){w3, w3} * v;
        }
    };

    int k = 0;
    for(; k + 8 <= T; k += 8){ body(rs + k + slot); body(rs + k + 4 + slot); }
    for(; k + 4 <= T; k += 4){ body(rs + k + slot); }
    if(k < T && slot < T - k){ body(rs + k + slot); }

    // reduce across the 4 slots (lanes with same pos)
    #pragma unroll
    for(int msk = 16; msk < 64; msk <<= 1){
        #pragma unroll
        for(int h = 0; h < 4; h++){
            #pragma unroll
            for(int p = 0; p < PAIRS; p++){
                acc[h][p][0] += __shfl_xor(acc[h][p][0], msk);
                acc[h][p][1] += __shfl_xor(acc[h][p][1], msk);
            }
            dnm[h] += __shfl_xor(dnm[h], msk);
        }
    }
    if(lane < 16){
        #pragma unroll
        for(int h = 0; h < 4; h++){
            const float sc = 1.f / dnm[h];
            if constexpr(PAIRS == 2){
                ushort4v o;
                o[0] = f2bf(acc[h][0][0] * sc); o[1] = f2bf(acc[h][0][1] * sc);
                o[2] = f2bf(acc[h][1][0] * sc); o[3] = f2bf(acc[h][1][1] * sc);
                *(ushort4v*)&g[(size_t)n * (4 * K) + h * K + pos * CPL] = o;
            } else {
                ushort8v o;
                #pragma unroll
                for(int p = 0; p < 4; p++){
                    o[2*p]   = f2bf(acc[h][p][0] * sc);
                    o[2*p+1] = f2bf(acc[h][p][1] * sc);
                }
                *(ushort8v*)&g[(size_t)n * (4 * K) + h * K + pos * CPL] = o;
            }
        }
    }
}

// ---------------- post-aggregation GEMM: out = g[n,KC] @ Wcat[KC,NC] (+bias, relu / log_softmax) ----------------
template<int KC, int NC, bool FINAL>
__global__ __launch_bounds__(256) void pgemm_kernel(const unsigned short* __restrict__ A,
                                                    const unsigned short* __restrict__ Bt,
                                                    const float* __restrict__ bias,
                                                    void* __restrict__ outv, int M){
    constexpr int NT = (NC + 15) / 16;   // 4 (NC=64) or 3 (NC=40)
    const int lane = threadIdx.x & 63;
    const int wave = threadIdx.x >> 6;
    const int quad = lane >> 4;
    const int l16 = lane & 15;
    const int bm = blockIdx.x * 64;
    const int m = min(bm + wave * 16 + l16, M - 1);
    const size_t arow = (size_t)m * KC;

    f32x4 acc[NT];
    #pragma unroll
    for(int t = 0; t < NT; t++) acc[t] = (f32x4){0,0,0,0};

    for(int k0 = 0; k0 < KC; k0 += 32){
        const short8v a = *(const short8v*)&A[arow + k0 + quad * 8];
        #pragma unroll
        for(int t = 0; t < NT; t++){
            const short8v b = *(const short8v*)&Bt[(size_t)(t * 16 + l16) * KC + k0 + quad * 8];
            acc[t] = __builtin_amdgcn_mfma_f32_16x16x32_bf16(a, b, acc[t], 0, 0, 0);
        }
    }
    const int rbase = bm + wave * 16 + quad * 4;
    if(!FINAL){
        unsigned short* out = (unsigned short*)outv;
        #pragma unroll
        for(int t = 0; t < NT; t++){
            const int c = t * 16 + l16;
            #pragma unroll
            for(int r = 0; r < 4; r++){
                const int row = rbase + r;
                if(row < M) out[(size_t)row * NC + c] = f2bf(fmaxf(acc[t][r] + bias[c], 0.f));
            }
        }
    } else {
        float* out = (float*)outv;
        float o[NT][4];
        #pragma unroll
        for(int t = 0; t < NT; t++){
            const int c = t * 16 + l16;
            const bool valid = c < 40;
            const float bc = valid ? bias[c] : 0.f;
            #pragma unroll
            for(int r = 0; r < 4; r++)
                o[t][r] = valid ? fmaxf(acc[t][r] + bc, 0.f) : -INFINITY;
        }
        #pragma unroll
        for(int r = 0; r < 4; r++){
            float mx = o[0][r];
            #pragma unroll
            for(int t = 1; t < NT; t++) mx = fmaxf(mx, o[t][r]);
            #pragma unroll
            for(int off = 1; off < 16; off <<= 1) mx = fmaxf(mx, __shfl_xor(mx, off));
            float se = 0.f;
            #pragma unroll
            for(int t = 0; t < NT; t++) se += (o[t][r] > -INFINITY) ? __expf(o[t][r] - mx) : 0.f;
            #pragma unroll
            for(int off = 1; off < 16; off <<= 1) se += __shfl_xor(se, off);
            const float lz = mx + logf(se);
            const int row = rbase + r;
            if(row < M){
                #pragma unroll
                for(int t = 0; t < NT; t++){
                    const int c = t * 16 + l16;
                    if(c < 40) out[(size_t)row * 40 + c] = o[t][r] - lz;
                }
            }
        }
    }
}

// ---------------- driver ----------------
extern "C" void kernel_launch(void* const* d_in, const int* in_sizes, int n_in,
                              void* d_out, int out_size, void* d_ws, size_t ws_size,
                              hipStream_t stream){
    const int N = NNODES;
    const int E = in_sizes[1] / 2;

    const float* x   = (const float*)d_in[0];
    const float* W1  = (const float*)d_in[2];
    const float* as1 = (const float*)d_in[3];
    const float* ad1 = (const float*)d_in[4];
    const float* b1  = (const float*)d_in[5];
    const float* W2  = (const float*)d_in[6];
    const float* as2 = (const float*)d_in[7];
    const float* ad2 = (const float*)d_in[8];
    const float* b2  = (const float*)d_in[9];
    const float* W3  = (const float*)d_in[10];
    const float* as3 = (const float*)d_in[11];
    const float* ad3 = (const float*)d_in[12];
    const float* b3  = (const float*)d_in[13];

    char* ws = (char*)d_ws;
    size_t off = 0;
    auto alloc = [&](size_t bytes) -> void* {
        void* p = ws + off;
        off = (off + bytes + 255) & ~(size_t)255;
        return p;
    };
    int*   flag    = (int*)  alloc(4);
    int*   row_ptr = (int*)  alloc((size_t)(N + 1) * 4);
    int*   colv    = (int*)  alloc((size_t)E * 4);
    int*   cursor  = (int*)  alloc((size_t)N * 4);
    int*   deg     = (int*)  alloc((size_t)N * 4);
    int*   excl    = (int*)  alloc((size_t)N * 4);
    int*   bsum    = (int*)  alloc(128 * 4);
    unsigned short* xbf = (unsigned short*)alloc((size_t)N * 128 * 2);
    unsigned short* Wa1 = (unsigned short*)alloc(16 * 128 * 2);
    unsigned short* Wa2 = (unsigned short*)alloc(16 * 64 * 2);
    unsigned short* Wa3 = (unsigned short*)alloc(16 * 64 * 2);
    unsigned short* Wc1 = (unsigned short*)alloc((size_t)64 * 512 * 2);
    unsigned short* Wc2 = (unsigned short*)alloc((size_t)64 * 256 * 2);
    unsigned short* Wc3 = (unsigned short*)alloc((size_t)48 * 256 * 2);
    float* eav     = (float*)alloc((size_t)N * 8 * 4);
    float* edv     = (float*)alloc((size_t)N * 8 * 4);
    unsigned short* g   = (unsigned short*)alloc((size_t)N * 512 * 2);  // g (max KC=512)
    unsigned short* h   = (unsigned short*)alloc((size_t)N * 64 * 2);
    (void)ws_size;

    const void* eraw = d_in[1];

    init_kernel<<<(N + 255) / 256, 256, 0, stream>>>((const unsigned long long*)eraw, flag, deg, N);
    hist_kernel<<<(E + 255) / 256, 256, 0, stream>>>(eraw, flag, deg, E);

    const int X4 = N * 128 / 4;
    const int prepTotal = X4 + 16*128 + 16*64 + 16*64 + 64*512 + 64*256 + 48*256;
    prep_kernel<<<(prepTotal + 255) / 256, 256, 0, stream>>>(x, xbf, X4,
                                                             W1, as1, ad1, W2, as2, ad2, W3, as3, ad3,
                                                             Wa1, Wa2, Wa3, Wc1, Wc2, Wc3);

    const int nbScan = (N + 511) / 512;
    scan1_kernel<<<nbScan, 512, 0, stream>>>(deg, excl, bsum, N);
    scan2_kernel<<<1, 128, 0, stream>>>(bsum, nbScan);
    scan3_kernel<<<(N + 255) / 256, 256, 0, stream>>>(excl, bsum, row_ptr, cursor, N, E);
    scatter_kernel<<<(E + 255) / 256, 256, 0, stream>>>(eraw, flag, cursor, colv, E);

    const int nodeBlocks = N / 4;              // 12500
    const int mBlocks = (N + 63) / 64;         // 782

    // layer 1: features x (K=128)
    agemm_kernel<128><<<mBlocks, 256, 0, stream>>>(xbf, Wa1, eav, edv, N);
    gather_kernel<128><<<nodeBlocks, 256, 0, stream>>>(xbf, row_ptr, colv, eav, edv, g);
    pgemm_kernel<512, 64, false><<<mBlocks, 256, 0, stream>>>(g, Wc1, b1, h, N);

    // layer 2: features h (K=64)
    agemm_kernel<64><<<mBlocks, 256, 0, stream>>>(h, Wa2, eav, edv, N);
    gather_kernel<64><<<nodeBlocks, 256, 0, stream>>>(h, row_ptr, colv, eav, edv, g);
    pgemm_kernel<256, 64, false><<<mBlocks, 256, 0, stream>>>(g, Wc2, b2, h, N);

    // layer 3: features h (K=64) + fused log_softmax
    agemm_kernel<64><<<mBlocks, 256, 0, stream>>>(h, Wa3, eav, edv, N);
    gather_kernel<64><<<nodeBlocks, 256, 0, stream>>>(h, row_ptr, colv, eav, edv, g);
    pgemm_kernel<256, 40, true><<<mBlocks, 256, 0, stream>>>(g, Wc3, b3, d_out, N);
}